// Round 5
// baseline (222.389 us; speedup 1.0000x reference)
//
#include <hip/hip_runtime.h>

#define NB 32
#define NT 2048
#define ND 512
#define NDQ 128   // ND / 4 (float4 per row)
#define NC 128    // t-chunks per batch
#define TC (NT / NC)   // 16 tokens per chunk

// ---------------------------------------------------------------------------
// Kernel 1: per-(batch, t-chunk) partial sums of x, |x|, x*w over the chunk.
// block = 128 threads = one float4 lane-set over D=512 (2 waves).
// grid = (NC, B) = 4096 blocks -> 16 blocks/CU, 32 waves/CU (full occupancy),
// fine-grained balance over variable sentence lengths. Fully-masked chunks
// exit immediately without writing; kernel 2 only reads active chunks.
// ---------------------------------------------------------------------------
__global__ __launch_bounds__(128) void vu_partial_kernel(
    const float* __restrict__ vs,       // [B,T,D]
    const int* __restrict__ slen,       // [B]
    const int* __restrict__ wseq,       // [B,T]
    const float* __restrict__ weights,  // [VOCAB]
    float4* __restrict__ ps,            // [B*NC*NDQ] sum
    float4* __restrict__ pa,            // [B*NC*NDQ] sum |x|
    float4* __restrict__ pw)            // [B*NC*NDQ] sum x*w
{
    const int c  = blockIdx.x;
    const int b  = blockIdx.y;
    const int dq = threadIdx.x;         // 0..127

    const int t0   = c * TC;
    const int len  = slen[b];
    const int tEnd = min(t0 + TC, len);
    if (t0 >= tEnd) return;             // fully masked chunk: no write needed

    __shared__ float w_lds[TC];         // per-token scalar weight
    if (threadIdx.x < TC) {
        const int t = t0 + threadIdx.x;
        w_lds[threadIdx.x] = (t < tEnd) ? weights[wseq[b * NT + t]] : 0.0f;
    }
    __syncthreads();

    float4 s  = make_float4(0.f, 0.f, 0.f, 0.f);
    float4 sa = make_float4(0.f, 0.f, 0.f, 0.f);
    float4 sw = make_float4(0.f, 0.f, 0.f, 0.f);

    const float4* __restrict__ vsq = (const float4*)vs + ((size_t)b * NT + t0) * NDQ + dq;
    const int n = tEnd - t0;
    #pragma unroll 4
    for (int i = 0; i < n; ++i) {
        const float4 v = vsq[(size_t)i * NDQ];
        const float  w = w_lds[i];
        s.x += v.x; s.y += v.y; s.z += v.z; s.w += v.w;
        sa.x += fabsf(v.x); sa.y += fabsf(v.y); sa.z += fabsf(v.z); sa.w += fabsf(v.w);
        sw.x = fmaf(v.x, w, sw.x); sw.y = fmaf(v.y, w, sw.y);
        sw.z = fmaf(v.z, w, sw.z); sw.w = fmaf(v.w, w, sw.w);
    }

    const size_t o = ((size_t)b * NC + c) * NDQ + dq;
    ps[o] = s;
    pa[o] = sa;
    pw[o] = sw;
}

// ---------------------------------------------------------------------------
// Kernel 2: fold the ACTIVE partials per (b,d): y = s/sa, y_hat = sw.
// 4096 threads, one float4 column each; only reads chunks c < ceil(len/TC),
// so never touches unwritten (poisoned) workspace.
// ---------------------------------------------------------------------------
__global__ __launch_bounds__(256) void vu_reduce_kernel(
    const float4* __restrict__ ps,
    const float4* __restrict__ pa,
    const float4* __restrict__ pw,
    const int* __restrict__ slen,
    float4* __restrict__ out)           // [2][B][NDQ] float4
{
    const int gid = blockIdx.x * 256 + threadIdx.x;   // [0, B*NDQ)
    if (gid >= NB * NDQ) return;
    const int b  = gid >> 7;
    const int dq = gid & (NDQ - 1);

    const int len  = slen[b];
    const int cEnd = (len + TC - 1) / TC;             // active chunks (>=1)

    float4 s  = make_float4(0.f, 0.f, 0.f, 0.f);
    float4 sa = make_float4(0.f, 0.f, 0.f, 0.f);
    float4 sw = make_float4(0.f, 0.f, 0.f, 0.f);
    for (int c = 0; c < cEnd; ++c) {
        const size_t o = ((size_t)b * NC + c) * NDQ + dq;
        const float4 a = ps[o];
        const float4 x = pa[o];
        const float4 w = pw[o];
        s.x += a.x; s.y += a.y; s.z += a.z; s.w += a.w;
        sa.x += x.x; sa.y += x.y; sa.z += x.z; sa.w += x.w;
        sw.x += w.x; sw.y += w.y; sw.z += w.z; sw.w += w.w;
    }
    float4 y;
    y.x = s.x / sa.x; y.y = s.y / sa.y; y.z = s.z / sa.z; y.w = s.w / sa.w;
    out[(size_t)b * NDQ + dq] = y;                       // y
    out[(size_t)NB * NDQ + (size_t)b * NDQ + dq] = sw;   // y_hat
}

extern "C" void kernel_launch(void* const* d_in, const int* in_sizes, int n_in,
                              void* d_out, int out_size, void* d_ws, size_t ws_size,
                              hipStream_t stream) {
    const float* vs      = (const float*)d_in[0];
    const int*   slen    = (const int*)d_in[1];
    const int*   wseq    = (const int*)d_in[2];
    const float* weights = (const float*)d_in[3];
    float4*      out     = (float4*)d_out;

    const size_t stride = (size_t)NB * NC * NDQ;   // float4 units per buffer
    float4* ps = (float4*)d_ws;
    float4* pa = ps + stride;
    float4* pw = pa + stride;

    dim3 g1(NC, NB);
    vu_partial_kernel<<<g1, 128, 0, stream>>>(vs, slen, wseq, weights, ps, pa, pw);

    const int n2 = NB * NDQ;                       // 4096 threads
    vu_reduce_kernel<<<(n2 + 255) / 256, 256, 0, stream>>>(ps, pa, pw, slen, out);
}

// Round 6
// 211.294 us; speedup vs baseline: 1.0525x; 1.0525x over previous
//
#include <hip/hip_runtime.h>

#define NB 32
#define NT 2048
#define ND 512
#define NDQ 128        // ND / 4 (float4 per row)
#define NC 64          // t-chunks per batch
#define TC (NT / NC)   // 32 tokens per chunk

// ---------------------------------------------------------------------------
// Kernel 1: per-(batch, t-chunk) partial sums of x, |x|, x*w over the chunk,
// accumulated DIRECTLY into a small global accumulator via atomicAdd.
// Each thread owns one float4 column (b, dq) -> within a block all atomic
// targets are unique; contention is only across the <=64 c-blocks of one
// batch. ~1.6M fire-and-forget f32 atomics total to 48K addresses.
// Fully-masked chunks exit without touching memory.
// ---------------------------------------------------------------------------
__global__ __launch_bounds__(128) void vu_partial_kernel(
    const float* __restrict__ vs,       // [B,T,D]
    const int* __restrict__ slen,       // [B]
    const int* __restrict__ wseq,       // [B,T]
    const float* __restrict__ weights,  // [VOCAB]
    float* __restrict__ accS,           // [B*ND] sum x
    float* __restrict__ accA,           // [B*ND] sum |x|
    float* __restrict__ accW)           // [B*ND] sum x*w
{
    const int c  = blockIdx.x;
    const int b  = blockIdx.y;
    const int dq = threadIdx.x;         // 0..127

    const int t0   = c * TC;
    const int len  = slen[b];
    const int tEnd = min(t0 + TC, len);
    if (t0 >= tEnd) return;             // fully masked chunk

    __shared__ float w_lds[TC];         // per-token scalar weight
    if (threadIdx.x < TC) {
        const int t = t0 + threadIdx.x;
        w_lds[threadIdx.x] = (t < tEnd) ? weights[wseq[b * NT + t]] : 0.0f;
    }
    __syncthreads();

    float4 s  = make_float4(0.f, 0.f, 0.f, 0.f);
    float4 sa = make_float4(0.f, 0.f, 0.f, 0.f);
    float4 sw = make_float4(0.f, 0.f, 0.f, 0.f);

    const float4* __restrict__ vsq =
        (const float4*)vs + ((size_t)b * NT + t0) * NDQ + dq;
    const int n = tEnd - t0;
    #pragma unroll 4
    for (int i = 0; i < n; ++i) {
        const float4 v = vsq[(size_t)i * NDQ];
        const float  w = w_lds[i];
        s.x += v.x; s.y += v.y; s.z += v.z; s.w += v.w;
        sa.x += fabsf(v.x); sa.y += fabsf(v.y); sa.z += fabsf(v.z); sa.w += fabsf(v.w);
        sw.x = fmaf(v.x, w, sw.x); sw.y = fmaf(v.y, w, sw.y);
        sw.z = fmaf(v.z, w, sw.z); sw.w = fmaf(v.w, w, sw.w);
    }

    const size_t o = (size_t)b * ND + (size_t)dq * 4;
    atomicAdd(&accS[o + 0], s.x);  atomicAdd(&accS[o + 1], s.y);
    atomicAdd(&accS[o + 2], s.z);  atomicAdd(&accS[o + 3], s.w);
    atomicAdd(&accA[o + 0], sa.x); atomicAdd(&accA[o + 1], sa.y);
    atomicAdd(&accA[o + 2], sa.z); atomicAdd(&accA[o + 3], sa.w);
    atomicAdd(&accW[o + 0], sw.x); atomicAdd(&accW[o + 1], sw.y);
    atomicAdd(&accW[o + 2], sw.z); atomicAdd(&accW[o + 3], sw.w);
}

// ---------------------------------------------------------------------------
// Kernel 2 (finalize): y = s/sa, y_hat = sw. 4096 threads, coalesced.
// ---------------------------------------------------------------------------
__global__ __launch_bounds__(256) void vu_final_kernel(
    const float4* __restrict__ accS,
    const float4* __restrict__ accA,
    const float4* __restrict__ accW,
    float4* __restrict__ out)           // [2][B][NDQ] float4
{
    const int gid = blockIdx.x * 256 + threadIdx.x;   // [0, B*NDQ)
    if (gid >= NB * NDQ) return;

    const float4 s  = accS[gid];
    const float4 sa = accA[gid];
    const float4 sw = accW[gid];
    float4 y;
    y.x = s.x / sa.x; y.y = s.y / sa.y; y.z = s.z / sa.z; y.w = s.w / sa.w;
    out[gid] = y;                        // y
    out[(size_t)NB * NDQ + gid] = sw;    // y_hat
}

extern "C" void kernel_launch(void* const* d_in, const int* in_sizes, int n_in,
                              void* d_out, int out_size, void* d_ws, size_t ws_size,
                              hipStream_t stream) {
    const float* vs      = (const float*)d_in[0];
    const int*   slen    = (const int*)d_in[1];
    const int*   wseq    = (const int*)d_in[2];
    const float* weights = (const float*)d_in[3];
    float4*      out     = (float4*)d_out;

    float* accS = (float*)d_ws;                 // [B*ND]
    float* accA = accS + (size_t)NB * ND;       // [B*ND]
    float* accW = accA + (size_t)NB * ND;       // [B*ND]

    // zero the 192 KB accumulator (ws is re-poisoned to 0xAA before each call)
    hipMemsetAsync(d_ws, 0, (size_t)3 * NB * ND * sizeof(float), stream);

    dim3 g1(NC, NB);
    vu_partial_kernel<<<g1, 128, 0, stream>>>(vs, slen, wseq, weights,
                                              accS, accA, accW);

    const int n2 = NB * NDQ;                    // 4096 threads
    vu_final_kernel<<<(n2 + 255) / 256, 256, 0, stream>>>(
        (const float4*)accS, (const float4*)accA, (const float4*)accW, out);
}

// Round 7
// 195.453 us; speedup vs baseline: 1.1378x; 1.0810x over previous
//
#include <hip/hip_runtime.h>

#define NB 32
#define NT 2048
#define ND 512
#define NDQ 128        // ND / 4 (float4 per row)
#define NC 64          // t-chunks per batch
#define TC (NT / NC)   // 32 tokens per chunk

// ---------------------------------------------------------------------------
// Kernel 1 (best-known R4 structure): per-(batch, t-chunk) partial sums of
// x, |x|, x*w. block = 128 threads = one float4 lane-set over D=512.
// grid = (NC, B) = 2048 blocks. Fully-masked chunks exit without writing;
// kernel 2 only reads active chunks.
// ---------------------------------------------------------------------------
__global__ __launch_bounds__(128) void vu_partial_kernel(
    const float* __restrict__ vs,       // [B,T,D]
    const int* __restrict__ slen,       // [B]
    const int* __restrict__ wseq,       // [B,T]
    const float* __restrict__ weights,  // [VOCAB]
    float4* __restrict__ ps,            // [B*NC*NDQ] sum
    float4* __restrict__ pa,            // [B*NC*NDQ] sum |x|
    float4* __restrict__ pw)            // [B*NC*NDQ] sum x*w
{
    const int c  = blockIdx.x;
    const int b  = blockIdx.y;
    const int dq = threadIdx.x;         // 0..127

    const int t0   = c * TC;
    const int len  = slen[b];
    const int tEnd = min(t0 + TC, len);
    if (t0 >= tEnd) return;             // fully masked chunk: no write needed

    __shared__ float w_lds[TC];         // per-token scalar weight
    if (threadIdx.x < TC) {
        const int t = t0 + threadIdx.x;
        w_lds[threadIdx.x] = (t < tEnd) ? weights[wseq[b * NT + t]] : 0.0f;
    }
    __syncthreads();

    float4 s  = make_float4(0.f, 0.f, 0.f, 0.f);
    float4 sa = make_float4(0.f, 0.f, 0.f, 0.f);
    float4 sw = make_float4(0.f, 0.f, 0.f, 0.f);

    const float4* __restrict__ vsq =
        (const float4*)vs + ((size_t)b * NT + t0) * NDQ + dq;
    const int n = tEnd - t0;
    #pragma unroll 4
    for (int i = 0; i < n; ++i) {
        const float4 v = vsq[(size_t)i * NDQ];
        const float  w = w_lds[i];
        s.x += v.x; s.y += v.y; s.z += v.z; s.w += v.w;
        sa.x += fabsf(v.x); sa.y += fabsf(v.y); sa.z += fabsf(v.z); sa.w += fabsf(v.w);
        sw.x = fmaf(v.x, w, sw.x); sw.y = fmaf(v.y, w, sw.y);
        sw.z = fmaf(v.z, w, sw.z); sw.w = fmaf(v.w, w, sw.w);
    }

    const size_t o = ((size_t)b * NC + c) * NDQ + dq;
    ps[o] = s;
    pa[o] = sa;
    pw[o] = sw;
}

// ---------------------------------------------------------------------------
// Kernel 2: one block per batch, 256 threads = 2 c-groups x 128 dq columns.
// Each group folds every other active chunk (stride 2), groups combine via
// LDS, group 0 writes y = s/sa and y_hat. Only active chunks are read.
// ---------------------------------------------------------------------------
__global__ __launch_bounds__(256) void vu_reduce_kernel(
    const float4* __restrict__ ps,
    const float4* __restrict__ pa,
    const float4* __restrict__ pw,
    const int* __restrict__ slen,
    float4* __restrict__ out)           // [2][B][NDQ] float4
{
    const int b  = blockIdx.x;
    const int dq = threadIdx.x & (NDQ - 1);
    const int tt = threadIdx.x >> 7;    // 0 or 1

    __shared__ float red[NDQ * 12];

    const int len  = slen[b];
    const int cEnd = (len + TC - 1) / TC;             // active chunks (>=1)

    float4 s  = make_float4(0.f, 0.f, 0.f, 0.f);
    float4 sa = make_float4(0.f, 0.f, 0.f, 0.f);
    float4 sw = make_float4(0.f, 0.f, 0.f, 0.f);
    for (int c = tt; c < cEnd; c += 2) {
        const size_t o = ((size_t)b * NC + c) * NDQ + dq;
        const float4 a = ps[o];
        const float4 x = pa[o];
        const float4 w = pw[o];
        s.x += a.x; s.y += a.y; s.z += a.z; s.w += a.w;
        sa.x += x.x; sa.y += x.y; sa.z += x.z; sa.w += x.w;
        sw.x += w.x; sw.y += w.y; sw.z += w.z; sw.w += w.w;
    }

    if (tt == 1) {
        float* r = &red[dq * 12];
        r[0] = s.x;  r[1] = s.y;  r[2]  = s.z;  r[3]  = s.w;
        r[4] = sa.x; r[5] = sa.y; r[6]  = sa.z; r[7]  = sa.w;
        r[8] = sw.x; r[9] = sw.y; r[10] = sw.z; r[11] = sw.w;
    }
    __syncthreads();
    if (tt == 0) {
        const float* r = &red[dq * 12];
        s.x += r[0];  s.y += r[1];  s.z += r[2];   s.w += r[3];
        sa.x += r[4]; sa.y += r[5]; sa.z += r[6];  sa.w += r[7];
        sw.x += r[8]; sw.y += r[9]; sw.z += r[10]; sw.w += r[11];
        float4 y;
        y.x = s.x / sa.x; y.y = s.y / sa.y; y.z = s.z / sa.z; y.w = s.w / sa.w;
        out[(size_t)b * NDQ + dq] = y;                       // y
        out[(size_t)NB * NDQ + (size_t)b * NDQ + dq] = sw;   // y_hat
    }
}

extern "C" void kernel_launch(void* const* d_in, const int* in_sizes, int n_in,
                              void* d_out, int out_size, void* d_ws, size_t ws_size,
                              hipStream_t stream) {
    const float* vs      = (const float*)d_in[0];
    const int*   slen    = (const int*)d_in[1];
    const int*   wseq    = (const int*)d_in[2];
    const float* weights = (const float*)d_in[3];
    float4*      out     = (float4*)d_out;

    const size_t stride = (size_t)NB * NC * NDQ;   // float4 units per buffer
    float4* ps = (float4*)d_ws;
    float4* pa = ps + stride;
    float4* pw = pa + stride;

    dim3 g1(NC, NB);
    vu_partial_kernel<<<g1, 128, 0, stream>>>(vs, slen, wseq, weights, ps, pa, pw);

    vu_reduce_kernel<<<NB, 256, 0, stream>>>(ps, pa, pw, slen, out);
}